// Round 1
// baseline (621.432 us; speedup 1.0000x reference)
//
#include <hip/hip_runtime.h>
#include <math.h>

// ---------------------------------------------------------------------------
// SupConLoss on MI355X.
// out = 0.5*CE(predicts,targets) + 0.5*nt_xent(Anorm, temp=0.1)
//       + 0.25*nt_xent2(Anorm, temp=0.05)
// Heavy part: G = Anorm * Anorm^T  (4096x4096x768 fp32 GEMM), then row-wise
// reductions over G. nt_xent2 collapses to per-class formula given per-row S.
// ---------------------------------------------------------------------------

__device__ __forceinline__ float blockReduceSum(float v, float* sbuf) {
#pragma unroll
  for (int o = 32; o > 0; o >>= 1) v += __shfl_down(v, o, 64);
  int lane = threadIdx.x & 63;
  int w = threadIdx.x >> 6;
  __syncthreads();  // protect sbuf reuse across consecutive calls
  if (lane == 0) sbuf[w] = v;
  __syncthreads();
  return sbuf[0] + sbuf[1] + sbuf[2] + sbuf[3];
}

__device__ __forceinline__ float blockReduceMax(float v, float* sbuf) {
#pragma unroll
  for (int o = 32; o > 0; o >>= 1) v = fmaxf(v, __shfl_down(v, o, 64));
  int lane = threadIdx.x & 63;
  int w = threadIdx.x >> 6;
  __syncthreads();
  if (lane == 0) sbuf[w] = v;
  __syncthreads();
  return fmaxf(fmaxf(sbuf[0], sbuf[1]), fmaxf(sbuf[2], sbuf[3]));
}

// --- 1. row-normalize cls_feats -> A --------------------------------------
__global__ void k_normalize(const float* __restrict__ X, float* __restrict__ A,
                            int D) {
  __shared__ float sbuf[8];
  int row = blockIdx.x;
  const float* x = X + (size_t)row * D;
  float* a = A + (size_t)row * D;
  float ss = 0.f;
  for (int j = threadIdx.x; j < D; j += blockDim.x) {
    float v = x[j];
    ss += v * v;
  }
  ss = blockReduceSum(ss, sbuf);
  float inv = 1.0f / fmaxf(sqrtf(ss), 1e-12f);
  for (int j = threadIdx.x; j < D; j += blockDim.x) a[j] = x[j] * inv;
}

// --- 2. per-row CE --------------------------------------------------------
__global__ void k_ce(const float* __restrict__ P, const int* __restrict__ tgt,
                     float* __restrict__ ce_row, int N, int C) {
  int r = blockIdx.x * blockDim.x + threadIdx.x;
  if (r >= N) return;
  const float* p = P + (size_t)r * C;
  float m = -INFINITY;
  for (int c = 0; c < C; ++c) m = fmaxf(m, p[c]);
  float s = 0.f;
  for (int c = 0; c < C; ++c) s += expf(p[c] - m);
  int t = tgt[r];
  float lp = p[t] - m - logf(s);
  ce_row[r] = -lp;
}

// --- 3. G = A * A^T (fp32 tiled GEMM, 64x64 tile, 4x4 per thread) ---------
__global__ __launch_bounds__(256) void k_gemm_aat(const float* __restrict__ A,
                                                  float* __restrict__ G, int N,
                                                  int K) {
  __shared__ float As[64][17];
  __shared__ float Bs[64][17];
  int tid = threadIdx.x;
  int tx = tid & 15;
  int ty = tid >> 4;
  int rowBase = blockIdx.y * 64;
  int colBase = blockIdx.x * 64;
  float c[4][4] = {};
  for (int k0 = 0; k0 < K; k0 += 16) {
#pragma unroll
    for (int l = 0; l < 4; ++l) {
      int idx = tid + l * 256;
      int r = idx >> 4, kk = idx & 15;
      As[r][kk] = A[(size_t)(rowBase + r) * K + k0 + kk];
      Bs[r][kk] = A[(size_t)(colBase + r) * K + k0 + kk];
    }
    __syncthreads();
#pragma unroll
    for (int kk = 0; kk < 16; ++kk) {
      float a[4], b[4];
#pragma unroll
      for (int e = 0; e < 4; ++e) a[e] = As[ty * 4 + e][kk];
#pragma unroll
      for (int e = 0; e < 4; ++e) b[e] = Bs[tx * 4 + e][kk];
#pragma unroll
      for (int i2 = 0; i2 < 4; ++i2)
#pragma unroll
        for (int j2 = 0; j2 < 4; ++j2) c[i2][j2] += a[i2] * b[j2];
    }
    __syncthreads();
  }
#pragma unroll
  for (int i2 = 0; i2 < 4; ++i2)
#pragma unroll
    for (int j2 = 0; j2 < 4; ++j2)
      G[(size_t)(rowBase + ty * 4 + i2) * N + colBase + tx * 4 + j2] =
          c[i2][j2];
}

// --- 4. per-row stats over G ----------------------------------------------
// pos1[i] = pcnt>0 ? psum*10/pcnt - max1 - log(s1+eps) : 0
// Srow[i] = sum over negatives of exp(G*20 - max2)     (nt_xent2's S)
__global__ void k_rowstats(const float* __restrict__ G,
                           const int* __restrict__ lab,
                           float* __restrict__ pos1, float* __restrict__ Srow,
                           int N) {
  extern __shared__ float row[];
  __shared__ float sbuf[8];
  int i = blockIdx.x;
  const float* g = G + (size_t)i * N;
  for (int j = threadIdx.x; j < N; j += blockDim.x) row[j] = g[j];
  __syncthreads();
  int li = lab[i];
  float max1 = -INFINITY, max2 = -INFINITY, psum = 0.f;
  float pcnt = 0.f;
  for (int j = threadIdx.x; j < N; j += blockDim.x) {
    float gg = row[j];
    float adt = (j == i) ? 0.f : gg * 10.f;  // diag zeroed in reference
    max1 = fmaxf(max1, adt);
    bool same = (lab[j] == li);
    if (same && (j != i)) {
      psum += gg;
      pcnt += 1.f;
    }
    if (!same) max2 = fmaxf(max2, gg * 20.f);
  }
  max1 = blockReduceMax(max1, sbuf);
  max2 = blockReduceMax(max2, sbuf);
  psum = blockReduceSum(psum, sbuf);
  pcnt = blockReduceSum(pcnt, sbuf);
  float m2 = (max2 == -INFINITY) ? 0.f : max2;  // row_has_neg handling
  float s1 = 0.f, s2 = 0.f;
  for (int j = threadIdx.x; j < N; j += blockDim.x) {
    float gg = row[j];
    float adt = (j == i) ? 0.f : gg * 10.f;
    s1 += expf(adt - max1);
    if (lab[j] != li) s2 += expf(gg * 20.f - m2);
  }
  s1 = blockReduceSum(s1, sbuf);
  s2 = blockReduceSum(s2, sbuf);
  if (threadIdx.x == 0) {
    float p1 = 0.f;
    if (pcnt > 0.5f) p1 = psum * 10.f / pcnt - max1 - logf(s1 + 1e-12f);
    pos1[i] = p1;
    Srow[i] = s2;
  }
}

// --- 5. finalize ----------------------------------------------------------
__global__ void k_final(const float* __restrict__ ce_row,
                        const float* __restrict__ pos1,
                        const float* __restrict__ Srow,
                        const int* __restrict__ lab, float* __restrict__ out,
                        int N, int C) {
  __shared__ float classS[64];
  __shared__ int classCnt[64];
  __shared__ float sbuf[8];
  if (threadIdx.x < 64) {
    classS[threadIdx.x] = 0.f;
    classCnt[threadIdx.x] = 0;
  }
  __syncthreads();
  float sumCe = 0.f, sumP1 = 0.f;
  for (int i = threadIdx.x; i < N; i += blockDim.x) {
    sumCe += ce_row[i];
    sumP1 += pos1[i];
    int l = lab[i];
    atomicAdd(&classS[l], Srow[i]);
    atomicAdd(&classCnt[l], 1);
  }
  sumCe = blockReduceSum(sumCe, sbuf);
  sumP1 = blockReduceSum(sumP1, sbuf);
  __syncthreads();
  if (threadIdx.x == 0) {
    float totS = 0.f;
    for (int c = 0; c < C; ++c) totS += classS[c];
    float l2sum = 0.f;
    for (int c = 0; c < C; ++c) {
      int cnt = classCnt[c];
      if (cnt >= 2) {  // rows of this class have positives
        float negs = (float)(N - cnt);
        float x = (totS - classS[c]) / negs;  // nds/negsum
        l2sum += (float)cnt * logf(x + 1e-12f);
      }
    }
    float ce = sumCe / (float)N;        // mean CE
    float ntx1 = -sumP1 / (float)N;     // nt_xent
    float ntx2 = l2sum / (float)N;      // nt_xent2 (= -mean(pos_logits2))
    out[0] = 0.5f * ce + 0.5f * ntx1 + 0.25f * ntx2;
  }
}

extern "C" void kernel_launch(void* const* d_in, const int* in_sizes, int n_in,
                              void* d_out, int out_size, void* d_ws,
                              size_t ws_size, hipStream_t stream) {
  const float* X = (const float*)d_in[0];   // cls_feats [N,D]
  const float* P = (const float*)d_in[1];   // predicts  [N,C]
  const int* tgt = (const int*)d_in[2];     // targets   [N]
  float* out = (float*)d_out;

  int N = in_sizes[2];
  int D = in_sizes[0] / N;
  int C = in_sizes[1] / N;

  float* ws = (float*)d_ws;
  float* A = ws;                        // N*D
  float* G = A + (size_t)N * D;         // N*N
  float* ce_row = G + (size_t)N * N;    // N
  float* pos1 = ce_row + N;             // N
  float* Srow = pos1 + N;               // N

  k_normalize<<<N, 256, 0, stream>>>(X, A, D);
  k_ce<<<(N + 255) / 256, 256, 0, stream>>>(P, tgt, ce_row, N, C);
  dim3 grid(N / 64, N / 64);
  k_gemm_aat<<<grid, 256, 0, stream>>>(A, G, N, D);
  k_rowstats<<<N, 256, N * sizeof(float), stream>>>(G, tgt, pos1, Srow, N);
  k_final<<<1, 256, 0, stream>>>(ce_row, pos1, Srow, tgt, out, N, C);
}

// Round 2
// 163.710 us; speedup vs baseline: 3.7959x; 3.7959x over previous
//
#include <hip/hip_runtime.h>
#include <hip/hip_bf16.h>
#include <math.h>

// ---------------------------------------------------------------------------
// SupConLoss on MI355X.
// out = 0.5*CE(predicts,targets) + 0.5*nt_xent(Anorm, temp=0.1)
//       + 0.25*nt_xent2(Anorm, temp=0.05)
// Heavy part: G = Anorm * Anorm^T. Round 2: bf16 MFMA GEMM (m97 structure:
// 128x128 tile, BK=32, global_load_lds width 16, 4 waves x 4x4 MFMA tiles).
// ---------------------------------------------------------------------------

typedef __attribute__((ext_vector_type(8))) short bf16x8;
typedef __attribute__((ext_vector_type(4))) float f32x4;

__device__ __forceinline__ float blockReduceSum(float v, float* sbuf) {
#pragma unroll
  for (int o = 32; o > 0; o >>= 1) v += __shfl_down(v, o, 64);
  int lane = threadIdx.x & 63;
  int w = threadIdx.x >> 6;
  __syncthreads();
  if (lane == 0) sbuf[w] = v;
  __syncthreads();
  return sbuf[0] + sbuf[1] + sbuf[2] + sbuf[3];
}

__device__ __forceinline__ float blockReduceMax(float v, float* sbuf) {
#pragma unroll
  for (int o = 32; o > 0; o >>= 1) v = fmaxf(v, __shfl_down(v, o, 64));
  int lane = threadIdx.x & 63;
  int w = threadIdx.x >> 6;
  __syncthreads();
  if (lane == 0) sbuf[w] = v;
  __syncthreads();
  return fmaxf(fmaxf(sbuf[0], sbuf[1]), fmaxf(sbuf[2], sbuf[3]));
}

// --- 1. row-normalize cls_feats -> A (bf16) --------------------------------
__global__ void k_normalize(const float* __restrict__ X,
                            unsigned short* __restrict__ Ab, int D) {
  __shared__ float sbuf[8];
  int row = blockIdx.x;
  const float* x = X + (size_t)row * D;
  unsigned short* a = Ab + (size_t)row * D;
  float ss = 0.f;
  for (int j = threadIdx.x; j < D; j += blockDim.x) {
    float v = x[j];
    ss += v * v;
  }
  ss = blockReduceSum(ss, sbuf);
  float inv = 1.0f / fmaxf(sqrtf(ss), 1e-12f);
  for (int j = threadIdx.x; j < D; j += blockDim.x) {
    union { __hip_bfloat16 h; unsigned short u; } cv;
    cv.h = __float2bfloat16(x[j] * inv);
    a[j] = cv.u;
  }
}

// --- 2. per-row CE --------------------------------------------------------
__global__ void k_ce(const float* __restrict__ P, const int* __restrict__ tgt,
                     float* __restrict__ ce_row, int N, int C) {
  int r = blockIdx.x * blockDim.x + threadIdx.x;
  if (r >= N) return;
  const float* p = P + (size_t)r * C;
  float m = -INFINITY;
  for (int c = 0; c < C; ++c) m = fmaxf(m, p[c]);
  float s = 0.f;
  for (int c = 0; c < C; ++c) s += expf(p[c] - m);
  int t = tgt[r];
  float lp = p[t] - m - logf(s);
  ce_row[r] = -lp;
}

// --- 3. G = A * A^T, bf16 MFMA --------------------------------------------
// 128x128 tile per block, BK=32, 256 threads = 4 waves in 2x2, each wave
// computes a 64x64 region as 4x4 of 16x16x32 MFMA tiles.
__global__ __launch_bounds__(256) void k_gemm_bf16(
    const unsigned short* __restrict__ A, float* __restrict__ G, int N,
    int K) {
  __shared__ unsigned short Asm[128 * 32];
  __shared__ unsigned short Bsm[128 * 32];
  const int t = threadIdx.x;
  const int lane = t & 63;
  const int w = t >> 6;
  const int rowBase = blockIdx.y * 128;
  const int colBase = blockIdx.x * 128;
  const int wr = (w >> 1) * 64;  // wave row offset in tile
  const int wc = (w & 1) * 64;   // wave col offset in tile
  f32x4 acc[4][4] = {};

  const int sr = t >> 2;        // staging row (0..63) within half-tile
  const int sc = (t & 3) * 8;   // staging col element (0,8,16,24)

  for (int k0 = 0; k0 < K; k0 += 32) {
#pragma unroll
    for (int p = 0; p < 2; ++p) {
      const unsigned short* ga =
          A + (size_t)(rowBase + p * 64 + sr) * K + k0 + sc;
      __builtin_amdgcn_global_load_lds(
          (const __attribute__((address_space(1))) unsigned int*)ga,
          (__attribute__((address_space(3))) unsigned int*)&Asm[p * 2048 +
                                                                t * 8],
          16, 0, 0);
      const unsigned short* gb =
          A + (size_t)(colBase + p * 64 + sr) * K + k0 + sc;
      __builtin_amdgcn_global_load_lds(
          (const __attribute__((address_space(1))) unsigned int*)gb,
          (__attribute__((address_space(3))) unsigned int*)&Bsm[p * 2048 +
                                                                t * 8],
          16, 0, 0);
    }
    __syncthreads();
    bf16x8 af[4], bf[4];
#pragma unroll
    for (int mt = 0; mt < 4; ++mt)
      af[mt] =
          *(const bf16x8*)&Asm[(wr + mt * 16 + (lane & 15)) * 32 +
                               (lane >> 4) * 8];
#pragma unroll
    for (int nt = 0; nt < 4; ++nt)
      bf[nt] =
          *(const bf16x8*)&Bsm[(wc + nt * 16 + (lane & 15)) * 32 +
                               (lane >> 4) * 8];
#pragma unroll
    for (int mt = 0; mt < 4; ++mt)
#pragma unroll
      for (int nt = 0; nt < 4; ++nt)
        acc[mt][nt] = __builtin_amdgcn_mfma_f32_16x16x32_bf16(
            af[mt], bf[nt], acc[mt][nt], 0, 0, 0);
    __syncthreads();
  }
  // epilogue: C/D layout col=lane&15, row=(lane>>4)*4+reg
#pragma unroll
  for (int mt = 0; mt < 4; ++mt) {
#pragma unroll
    for (int nt = 0; nt < 4; ++nt) {
      int col = colBase + wc + nt * 16 + (lane & 15);
      int row0 = rowBase + wr + mt * 16 + (lane >> 4) * 4;
#pragma unroll
      for (int r = 0; r < 4; ++r)
        G[(size_t)(row0 + r) * N + col] = acc[mt][nt][r];
    }
  }
}

// --- 4. per-row stats over G ----------------------------------------------
__global__ void k_rowstats(const float* __restrict__ G,
                           const int* __restrict__ lab,
                           float* __restrict__ pos1, float* __restrict__ Srow,
                           int N) {
  extern __shared__ float row[];
  __shared__ float sbuf[8];
  int i = blockIdx.x;
  const float* g = G + (size_t)i * N;
  for (int j = threadIdx.x; j < N; j += blockDim.x) row[j] = g[j];
  __syncthreads();
  int li = lab[i];
  float max1 = -INFINITY, max2 = -INFINITY, psum = 0.f;
  float pcnt = 0.f;
  for (int j = threadIdx.x; j < N; j += blockDim.x) {
    float gg = row[j];
    float adt = (j == i) ? 0.f : gg * 10.f;
    max1 = fmaxf(max1, adt);
    bool same = (lab[j] == li);
    if (same && (j != i)) {
      psum += gg;
      pcnt += 1.f;
    }
    if (!same) max2 = fmaxf(max2, gg * 20.f);
  }
  max1 = blockReduceMax(max1, sbuf);
  max2 = blockReduceMax(max2, sbuf);
  psum = blockReduceSum(psum, sbuf);
  pcnt = blockReduceSum(pcnt, sbuf);
  float m2 = (max2 == -INFINITY) ? 0.f : max2;
  float s1 = 0.f, s2 = 0.f;
  for (int j = threadIdx.x; j < N; j += blockDim.x) {
    float gg = row[j];
    float adt = (j == i) ? 0.f : gg * 10.f;
    s1 += expf(adt - max1);
    if (lab[j] != li) s2 += expf(gg * 20.f - m2);
  }
  s1 = blockReduceSum(s1, sbuf);
  s2 = blockReduceSum(s2, sbuf);
  if (threadIdx.x == 0) {
    float p1 = 0.f;
    if (pcnt > 0.5f) p1 = psum * 10.f / pcnt - max1 - logf(s1 + 1e-12f);
    pos1[i] = p1;
    Srow[i] = s2;
  }
}

// --- 5. finalize ----------------------------------------------------------
__global__ void k_final(const float* __restrict__ ce_row,
                        const float* __restrict__ pos1,
                        const float* __restrict__ Srow,
                        const int* __restrict__ lab, float* __restrict__ out,
                        int N, int C) {
  __shared__ float classS[64];
  __shared__ int classCnt[64];
  __shared__ float sbuf[8];
  if (threadIdx.x < 64) {
    classS[threadIdx.x] = 0.f;
    classCnt[threadIdx.x] = 0;
  }
  __syncthreads();
  float sumCe = 0.f, sumP1 = 0.f;
  for (int i = threadIdx.x; i < N; i += blockDim.x) {
    sumCe += ce_row[i];
    sumP1 += pos1[i];
    int l = lab[i];
    atomicAdd(&classS[l], Srow[i]);
    atomicAdd(&classCnt[l], 1);
  }
  sumCe = blockReduceSum(sumCe, sbuf);
  sumP1 = blockReduceSum(sumP1, sbuf);
  __syncthreads();
  if (threadIdx.x == 0) {
    float totS = 0.f;
    for (int c = 0; c < C; ++c) totS += classS[c];
    float l2sum = 0.f;
    for (int c = 0; c < C; ++c) {
      int cnt = classCnt[c];
      if (cnt >= 2) {
        float negs = (float)(N - cnt);
        float x = (totS - classS[c]) / negs;
        l2sum += (float)cnt * logf(x + 1e-12f);
      }
    }
    float ce = sumCe / (float)N;
    float ntx1 = -sumP1 / (float)N;
    float ntx2 = l2sum / (float)N;
    out[0] = 0.5f * ce + 0.5f * ntx1 + 0.25f * ntx2;
  }
}

extern "C" void kernel_launch(void* const* d_in, const int* in_sizes, int n_in,
                              void* d_out, int out_size, void* d_ws,
                              size_t ws_size, hipStream_t stream) {
  const float* X = (const float*)d_in[0];  // cls_feats [N,D]
  const float* P = (const float*)d_in[1];  // predicts  [N,C]
  const int* tgt = (const int*)d_in[2];    // targets   [N]
  float* out = (float*)d_out;

  int N = in_sizes[2];
  int D = in_sizes[0] / N;
  int C = in_sizes[1] / N;

  char* ws = (char*)d_ws;
  unsigned short* Ab = (unsigned short*)ws;            // N*D bf16
  float* G = (float*)(ws + (size_t)N * D * 2);         // N*N f32
  float* ce_row = G + (size_t)N * N;                   // N
  float* pos1 = ce_row + N;                            // N
  float* Srow = pos1 + N;                              // N

  k_normalize<<<N, 256, 0, stream>>>(X, Ab, D);
  k_ce<<<(N + 255) / 256, 256, 0, stream>>>(P, tgt, ce_row, N, C);
  dim3 grid(N / 128, N / 128);
  k_gemm_bf16<<<grid, 256, 0, stream>>>(Ab, G, N, D);
  k_rowstats<<<N, 256, N * sizeof(float), stream>>>(G, tgt, pos1, Srow, N);
  k_final<<<1, 256, 0, stream>>>(ce_row, pos1, Srow, tgt, out, N, C);
}

// Round 3
// 153.448 us; speedup vs baseline: 4.0498x; 1.0669x over previous
//
#include <hip/hip_runtime.h>
#include <hip/hip_bf16.h>
#include <math.h>

// ---------------------------------------------------------------------------
// SupConLoss on MI355X.
// out = 0.5*CE(predicts,targets) + 0.5*nt_xent(Anorm, temp=0.1)
//       + 0.25*nt_xent2(Anorm, temp=0.05)
// Round 3: symmetric fused GEMM+stats. Only upper-triangular 128x128 tiles
// (528 blocks); each tile's stats are accumulated for BOTH row-strips via an
// LDS tile (aliased over staging LDS). G is never materialized: per
// (row, colblock) partials (psum, s1_raw, s2_raw, max2) -> merge -> final.
// All exp sums are computed UNSHIFTED (|exponent| <= 20, safe in fp32);
// the reference's row-max shift for S_j is applied exactly in the merge:
// S_j = s2_raw_total * exp(-max2_j).
// ---------------------------------------------------------------------------

typedef __attribute__((ext_vector_type(8))) short bf16x8;
typedef __attribute__((ext_vector_type(4))) float f32x4;

__device__ __forceinline__ float blockReduceSum(float v, float* sbuf) {
#pragma unroll
  for (int o = 32; o > 0; o >>= 1) v += __shfl_down(v, o, 64);
  int lane = threadIdx.x & 63;
  int w = threadIdx.x >> 6;
  __syncthreads();
  if (lane == 0) sbuf[w] = v;
  __syncthreads();
  return sbuf[0] + sbuf[1] + sbuf[2] + sbuf[3];
}

// --- 1. row-normalize cls_feats -> A (bf16) --------------------------------
__global__ void k_normalize(const float* __restrict__ X,
                            unsigned short* __restrict__ Ab, int D) {
  __shared__ float sbuf[8];
  int row = blockIdx.x;
  const float* x = X + (size_t)row * D;
  unsigned short* a = Ab + (size_t)row * D;
  float ss = 0.f;
  for (int j = threadIdx.x; j < D; j += blockDim.x) {
    float v = x[j];
    ss += v * v;
  }
  ss = blockReduceSum(ss, sbuf);
  float inv = 1.0f / fmaxf(sqrtf(ss), 1e-12f);
  for (int j = threadIdx.x; j < D; j += blockDim.x) {
    union { __hip_bfloat16 h; unsigned short u; } cv;
    cv.h = __float2bfloat16(x[j] * inv);
    a[j] = cv.u;
  }
}

// --- 2. per-row CE --------------------------------------------------------
__global__ void k_ce(const float* __restrict__ P, const int* __restrict__ tgt,
                     float* __restrict__ ce_row, int N, int C) {
  int r = blockIdx.x * blockDim.x + threadIdx.x;
  if (r >= N) return;
  const float* p = P + (size_t)r * C;
  float m = -INFINITY;
  for (int c = 0; c < C; ++c) m = fmaxf(m, p[c]);
  float s = 0.f;
  for (int c = 0; c < C; ++c) s += expf(p[c] - m);
  int t = tgt[r];
  float lp = p[t] - m - logf(s);
  ce_row[r] = -lp;
}

// --- 3. fused symmetric GEMM + per-tile stats ------------------------------
// Grid: 528 triangular blocks (by >= bx). 256 threads = 4 waves (2x2),
// 128x128 tile, BK=32, 16x16x32 bf16 MFMA, global_load_lds width 16.
// Epilogue: tile -> LDS (stride 129), A-side stats for rows (cols of bx),
// B-side stats (transposed read) for rows of strip bx (cols of by).
// part layout: float4 part[N][NB]; (psum, s1_raw, s2_raw, max2).
__global__ __launch_bounds__(256) void k_gemm_fused(
    const unsigned short* __restrict__ A, const int* __restrict__ lab,
    float4* __restrict__ part, int N, int K, int NB) {
  __shared__ __align__(16) char smem[128 * 129 * 4 + 128 * 2 * 16];
  __shared__ int labR[128];
  __shared__ int labC[128];
  unsigned short* Asm = (unsigned short*)smem;            // 8 KB (K-loop)
  unsigned short* Bsm = (unsigned short*)(smem + 8192);   // 8 KB (K-loop)
  float* T = (float*)smem;                                // 66048 B (epilogue)
  float4* red = (float4*)(smem + 128 * 129 * 4);          // 4 KB (epilogue)

  // triangular decode: bid -> (by, bx), by >= bx
  int bid = blockIdx.x;
  int by = (int)((sqrtf(8.f * (float)bid + 1.f) - 1.f) * 0.5f);
  while ((by + 1) * (by + 2) / 2 <= bid) ++by;
  while (by * (by + 1) / 2 > bid) --by;
  int bx = bid - by * (by + 1) / 2;

  const int t = threadIdx.x;
  const int lane = t & 63;
  const int w = t >> 6;
  const int rowBase = by * 128;
  const int colBase = bx * 128;
  const int wr = (w >> 1) * 64;
  const int wc = (w & 1) * 64;

  if (t < 128) labR[t] = lab[rowBase + t];
  else labC[t - 128] = lab[colBase + (t - 128)];

  f32x4 acc[4][4] = {};
  const int sr = t >> 2;
  const int sc = (t & 3) * 8;

  for (int k0 = 0; k0 < K; k0 += 32) {
#pragma unroll
    for (int p = 0; p < 2; ++p) {
      const unsigned short* ga =
          A + (size_t)(rowBase + p * 64 + sr) * K + k0 + sc;
      __builtin_amdgcn_global_load_lds(
          (const __attribute__((address_space(1))) unsigned int*)ga,
          (__attribute__((address_space(3))) unsigned int*)&Asm[p * 2048 +
                                                                t * 8],
          16, 0, 0);
      const unsigned short* gb =
          A + (size_t)(colBase + p * 64 + sr) * K + k0 + sc;
      __builtin_amdgcn_global_load_lds(
          (const __attribute__((address_space(1))) unsigned int*)gb,
          (__attribute__((address_space(3))) unsigned int*)&Bsm[p * 2048 +
                                                                t * 8],
          16, 0, 0);
    }
    __syncthreads();
    bf16x8 af[4], bf[4];
#pragma unroll
    for (int mt = 0; mt < 4; ++mt)
      af[mt] = *(const bf16x8*)&Asm[(wr + mt * 16 + (lane & 15)) * 32 +
                                    (lane >> 4) * 8];
#pragma unroll
    for (int nt = 0; nt < 4; ++nt)
      bf[nt] = *(const bf16x8*)&Bsm[(wc + nt * 16 + (lane & 15)) * 32 +
                                    (lane >> 4) * 8];
#pragma unroll
    for (int mt = 0; mt < 4; ++mt)
#pragma unroll
      for (int nt = 0; nt < 4; ++nt)
        acc[mt][nt] = __builtin_amdgcn_mfma_f32_16x16x32_bf16(
            af[mt], bf[nt], acc[mt][nt], 0, 0, 0);
    __syncthreads();
  }

  // ---- epilogue: tile -> LDS (stride 129) --------------------------------
#pragma unroll
  for (int mt = 0; mt < 4; ++mt)
#pragma unroll
    for (int nt = 0; nt < 4; ++nt) {
      int col = wc + nt * 16 + (lane & 15);
      int row0 = wr + mt * 16 + (lane >> 4) * 4;
#pragma unroll
      for (int r = 0; r < 4; ++r) T[(row0 + r) * 129 + col] = acc[mt][nt][r];
    }
  __syncthreads();

  // ---- A-side stats: rows of strip by, cols of strip bx ------------------
  {
    int row = t >> 1, h = t & 1;
    int gRow = rowBase + row;
    int lr = labR[row];
    const float* trow = T + row * 129 + h * 64;
    float psum = 0.f, s1 = 0.f, s2 = 0.f, m2 = -1e30f;
    for (int c0 = 0; c0 < 64; ++c0) {
      int c = h * 64 + c0;
      float v = trow[c0];
      int lc = labC[c];
      bool diag = (gRow == colBase + c);
      bool same = (lr == lc);
      float adt = diag ? 0.f : v * 10.f;
      float v20 = v * 20.f;
      float e1 = expf(adt);
      float e2 = expf(v20);
      s1 += e1;
      psum += (same && !diag) ? v : 0.f;
      bool neg = !same;
      s2 += neg ? e2 : 0.f;
      m2 = neg ? fmaxf(m2, v20) : m2;
    }
    red[row * 2 + h] = make_float4(psum, s1, s2, m2);
  }
  __syncthreads();
  if (t < 128) {
    float4 a = red[t * 2], b = red[t * 2 + 1];
    part[(size_t)(rowBase + t) * NB + bx] =
        make_float4(a.x + b.x, a.y + b.y, a.z + b.z, fmaxf(a.w, b.w));
  }

  // ---- B-side stats (transposed): rows of strip bx, cols of strip by -----
  if (by != bx) {
    __syncthreads();  // protect red reuse
    {
      int cc = t >> 1, h = t & 1;
      int lc = labC[cc];
      float psum = 0.f, s1 = 0.f, s2 = 0.f, m2 = -1e30f;
      for (int k0 = 0; k0 < 64; ++k0) {
        int k = h * 64 + k0;
        float v = T[k * 129 + cc];
        int lr2 = labR[k];
        bool same = (lr2 == lc);
        float v20 = v * 20.f;
        float e1 = expf(v * 10.f);
        float e2 = expf(v20);
        s1 += e1;
        psum += same ? v : 0.f;
        s2 += same ? 0.f : e2;
        m2 = same ? m2 : fmaxf(m2, v20);
      }
      red[cc * 2 + h] = make_float4(psum, s1, s2, m2);
    }
    __syncthreads();
    if (t < 128) {
      float4 a = red[t * 2], b = red[t * 2 + 1];
      part[(size_t)(colBase + t) * NB + by] =
          make_float4(a.x + b.x, a.y + b.y, a.z + b.z, fmaxf(a.w, b.w));
    }
  }
}

// --- 4. merge partials per row --------------------------------------------
// wave per row; lanes 0..31 read the 32 colblock partials.
__global__ void k_merge(const float4* __restrict__ part,
                        float* __restrict__ psumRow,
                        float* __restrict__ logS1, float* __restrict__ Srow,
                        int N, int NB) {
  int lane = threadIdx.x & 63;
  int w = threadIdx.x >> 6;
  int row = blockIdx.x * 4 + w;
  float ps = 0.f, s1 = 0.f, s2 = 0.f, m2 = -1e30f;
  if (lane < NB) {
    float4 p = part[(size_t)row * NB + lane];
    ps = p.x; s1 = p.y; s2 = p.z; m2 = p.w;
  }
#pragma unroll
  for (int o = 16; o > 0; o >>= 1) {
    ps += __shfl_down(ps, o, 64);
    s1 += __shfl_down(s1, o, 64);
    s2 += __shfl_down(s2, o, 64);
    m2 = fmaxf(m2, __shfl_down(m2, o, 64));
  }
  if (lane == 0) {
    psumRow[row] = ps;
    logS1[row] = logf(s1);
    Srow[row] = (m2 < -1e29f) ? 0.f : s2 * expf(-m2);
  }
}

// --- 5. finalize ----------------------------------------------------------
__global__ void k_final(const float* __restrict__ ce_row,
                        const float* __restrict__ psumRow,
                        const float* __restrict__ logS1,
                        const float* __restrict__ Srow,
                        const int* __restrict__ lab, float* __restrict__ out,
                        int N, int C) {
  __shared__ float classS[32];
  __shared__ int classCnt[32];
  __shared__ float sbuf[8];
  if (threadIdx.x < 32) {
    classS[threadIdx.x] = 0.f;
    classCnt[threadIdx.x] = 0;
  }
  __syncthreads();
  float sumCe = 0.f;
  for (int i = threadIdx.x; i < N; i += blockDim.x) {
    sumCe += ce_row[i];
    int l = lab[i];
    atomicAdd(&classCnt[l], 1);
    atomicAdd(&classS[l], Srow[i]);
  }
  __syncthreads();
  float sumP1 = 0.f;
  for (int i = threadIdx.x; i < N; i += blockDim.x) {
    int l = lab[i];
    int pc = classCnt[l] - 1;
    if (pc > 0) sumP1 += psumRow[i] * 10.f / (float)pc - logS1[i];
  }
  sumCe = blockReduceSum(sumCe, sbuf);
  sumP1 = blockReduceSum(sumP1, sbuf);
  if (threadIdx.x == 0) {
    float totS = 0.f;
    for (int c = 0; c < C; ++c) totS += classS[c];
    float l2sum = 0.f;
    for (int c = 0; c < C; ++c) {
      int cnt = classCnt[c];
      if (cnt >= 2) {
        float negs = (float)(N - cnt);
        float x = (totS - classS[c]) / negs;
        l2sum += (float)cnt * logf(x + 1e-12f);
      }
    }
    float ce = sumCe / (float)N;
    float ntx1 = -sumP1 / (float)N;
    float ntx2 = l2sum / (float)N;
    out[0] = 0.5f * ce + 0.5f * ntx1 + 0.25f * ntx2;
  }
}

extern "C" void kernel_launch(void* const* d_in, const int* in_sizes, int n_in,
                              void* d_out, int out_size, void* d_ws,
                              size_t ws_size, hipStream_t stream) {
  const float* X = (const float*)d_in[0];  // cls_feats [N,D]
  const float* P = (const float*)d_in[1];  // predicts  [N,C]
  const int* tgt = (const int*)d_in[2];    // targets   [N]
  float* out = (float*)d_out;

  int N = in_sizes[2];
  int D = in_sizes[0] / N;
  int C = in_sizes[1] / N;
  int NB = N / 128;

  char* ws = (char*)d_ws;
  unsigned short* Ab = (unsigned short*)ws;               // N*D bf16
  float4* part = (float4*)(ws + (size_t)N * D * 2);       // N*NB float4
  float* ce_row = (float*)((char*)part + (size_t)N * NB * 16);
  float* psumRow = ce_row + N;
  float* logS1 = psumRow + N;
  float* Srow = logS1 + N;

  k_normalize<<<N, 256, 0, stream>>>(X, Ab, D);
  k_ce<<<(N + 255) / 256, 256, 0, stream>>>(P, tgt, ce_row, N, C);
  int nblk = NB * (NB + 1) / 2;
  k_gemm_fused<<<nblk, 256, 0, stream>>>(Ab, tgt, part, N, D, NB);
  k_merge<<<N / 4, 256, 0, stream>>>(part, psumRow, logS1, Srow, N, NB);
  k_final<<<1, 256, 0, stream>>>(ce_row, psumRow, logS1, Srow, tgt, out, N, C);
}